// Round 9
// baseline (2301.322 us; speedup 1.0000x reference)
//
#include <hip/hip_runtime.h>

#define NLEVELS 16
#define TSIZE 131072
#define TMASK (TSIZE - 1)
#define NBUCK 32768           // 8 trees x 4096 morton cells (4 bits/dim)

typedef float f32x4 __attribute__((ext_vector_type(4)));

__device__ __constant__ float RM1_TAB[16] = {
    15.f, 21.f, 29.f, 40.f, 54.f, 74.f, 101.f, 138.f,
    187.f, 255.f, 347.f, 471.f, 641.f, 871.f, 1183.f, 1607.f
};

// spread 4 bits to stride-3 positions 0,3,6,9
__device__ __forceinline__ unsigned spread4(unsigned v) {
    v = (v | (v << 4)) & 0x0C3u;
    v = (v | (v << 2)) & 0x249u;
    return v;
}

__device__ __forceinline__ unsigned bucket_key(float x, float y, float z, unsigned tree) {
    const int cx = min(max((int)((x * 0.5f + 0.5f) * 16.f), 0), 15);
    const int cy = min(max((int)((y * 0.5f + 0.5f) * 16.f), 0), 15);
    const int cz = min(max((int)((z * 0.5f + 0.5f) * 16.f), 0), 15);
    const unsigned m = spread4((unsigned)cx) | (spread4((unsigned)cy) << 1)
                     | (spread4((unsigned)cz) << 2);
    return (tree << 12) | m;
}

// ---------------- counting sort by (tree, morton12) ----------------

__global__ __launch_bounds__(256) void k_hist(const float* __restrict__ xs,
                                              const int* __restrict__ inds, int N,
                                              unsigned* __restrict__ hist) {
    const int i = blockIdx.x * 256 + threadIdx.x;
    if (i >= N) return;
    const unsigned key = bucket_key(xs[3 * i], xs[3 * i + 1], xs[3 * i + 2],
                                    (unsigned)(inds[i] & 7));
    atomicAdd(&hist[key], 1u);
}

__global__ __launch_bounds__(1024) void k_scan(const unsigned* __restrict__ hist,
                                               unsigned* __restrict__ cursor) {
    __shared__ unsigned sums[1024];
    const int t = threadIdx.x;
    const int per = NBUCK / 1024;          // 32
    unsigned s = 0;
    #pragma unroll
    for (int j = 0; j < per; ++j) s += hist[t * per + j];
    sums[t] = s;
    __syncthreads();
    for (int off = 1; off < 1024; off <<= 1) {
        const unsigned add = (t >= off) ? sums[t - off] : 0u;
        __syncthreads();
        sums[t] += add;
        __syncthreads();
    }
    unsigned run = (t == 0) ? 0u : sums[t - 1];
    #pragma unroll
    for (int j = 0; j < per; ++j) {
        cursor[t * per + j] = run;
        run += hist[t * per + j];
    }
}

__global__ __launch_bounds__(256) void k_scatter(const float* __restrict__ xs,
                                                 const int* __restrict__ inds, int N,
                                                 unsigned* __restrict__ cursor,
                                                 float4* __restrict__ sorted) {
    const int i = blockIdx.x * 256 + threadIdx.x;
    if (i >= N) return;
    const float x = xs[3 * i], y = xs[3 * i + 1], z = xs[3 * i + 2];
    const unsigned tree = (unsigned)(inds[i] & 7);
    const unsigned key = bucket_key(x, y, z, tree);
    const unsigned pos = atomicAdd(&cursor[key], 1u);
    sorted[pos] = make_float4(x, y, z, __uint_as_float(((unsigned)i) | (tree << 24)));
}

// ---------------- per-level helpers (forceinline, constant l under unroll) --

__device__ __forceinline__ void level_load(const float4 p, int tree, int l,
                                           const float* __restrict__ params,
                                           float2 f[8],
                                           float& wx, float& wy, float& wz) {
    const float rm1 = RM1_TAB[l];
    const int rmax = (int)rm1;

    const float px = (p.x * 0.5f + 0.5f) * rm1;
    const float py = (p.y * 0.5f + 0.5f) * rm1;
    const float pz = (p.z * 0.5f + 0.5f) * rm1;
    const float fx = floorf(px), fy = floorf(py), fz = floorf(pz);
    wx = px - fx; wy = py - fy; wz = pz - fz;
    const int ix = (int)fx, iy = (int)fy, iz = (int)fz;

    const int x0 = min(max(ix, 0), rmax), x1 = min(max(ix + 1, 0), rmax);
    const int y0 = min(max(iy, 0), rmax), y1 = min(max(iy + 1, 0), rmax);
    const int z0 = min(max(iz, 0), rmax), z1 = min(max(iz + 1, 0), rmax);

    const unsigned hx0 = (unsigned)x0;
    const unsigned hx1 = (unsigned)x1;
    const unsigned hy0 = (unsigned)y0 * 2654435761u;
    const unsigned hy1 = (unsigned)y1 * 2654435761u;
    const unsigned hz0 = (unsigned)z0 * 805459861u;
    const unsigned hz1 = (unsigned)z1 * 805459861u;

    const float2* __restrict__ tbl =
        (const float2*)(params + (size_t)(tree * NLEVELS + l) * (TSIZE * 2));

    const unsigned m00 = hy0 ^ hz0;
    const unsigned m01 = hy0 ^ hz1;
    const unsigned m10 = hy1 ^ hz0;
    const unsigned m11 = hy1 ^ hz1;
    const unsigned i000 = (hx0 ^ m00) & TMASK;
    const unsigned i001 = (hx0 ^ m01) & TMASK;
    const unsigned i010 = (hx0 ^ m10) & TMASK;
    const unsigned i011 = (hx0 ^ m11) & TMASK;

    // x-prime is 1: if x0 even and x1==x0+1, the two x-corners are ADJACENT
    // table entries {2j,2j+1} -> one aligned float4 covers both.
    const bool pairOK = ((x0 & 1) == 0) && (x1 == x0 + 1);
    if (pairOK) {
        const float4* __restrict__ tbl4 = (const float4*)tbl;
        const float4 q00 = tbl4[i000 >> 1];
        const float4 q01 = tbl4[i001 >> 1];
        const float4 q10 = tbl4[i010 >> 1];
        const float4 q11 = tbl4[i011 >> 1];
        f[0] = (i000 & 1) ? make_float2(q00.z, q00.w) : make_float2(q00.x, q00.y);
        f[4] = (i000 & 1) ? make_float2(q00.x, q00.y) : make_float2(q00.z, q00.w);
        f[1] = (i001 & 1) ? make_float2(q01.z, q01.w) : make_float2(q01.x, q01.y);
        f[5] = (i001 & 1) ? make_float2(q01.x, q01.y) : make_float2(q01.z, q01.w);
        f[2] = (i010 & 1) ? make_float2(q10.z, q10.w) : make_float2(q10.x, q10.y);
        f[6] = (i010 & 1) ? make_float2(q10.x, q10.y) : make_float2(q10.z, q10.w);
        f[3] = (i011 & 1) ? make_float2(q11.z, q11.w) : make_float2(q11.x, q11.y);
        f[7] = (i011 & 1) ? make_float2(q11.x, q11.y) : make_float2(q11.z, q11.w);
    } else {
        const unsigned i100 = (hx1 ^ m00) & TMASK;
        const unsigned i101 = (hx1 ^ m01) & TMASK;
        const unsigned i110 = (hx1 ^ m10) & TMASK;
        const unsigned i111 = (hx1 ^ m11) & TMASK;
        f[0] = tbl[i000]; f[1] = tbl[i001];
        f[2] = tbl[i010]; f[3] = tbl[i011];
        f[4] = tbl[i100]; f[5] = tbl[i101];
        f[6] = tbl[i110]; f[7] = tbl[i111];
    }
}

__device__ __forceinline__ float2 level_fma(const float2 f[8],
                                            float wx, float wy, float wz) {
    const float wx0 = 1.f - wx, wy0 = 1.f - wy, wz0 = 1.f - wz;
    const float w0 = wx0 * wy0 * wz0;
    const float w1 = wx0 * wy0 * wz;
    const float w2 = wx0 * wy  * wz0;
    const float w3 = wx0 * wy  * wz;
    const float w4 = wx  * wy0 * wz0;
    const float w5 = wx  * wy0 * wz;
    const float w6 = wx  * wy  * wz0;
    const float w7 = wx  * wy  * wz;
    float a0 = 0.f, a1 = 0.f;
    a0 = fmaf(w0, f[0].x, a0); a1 = fmaf(w0, f[0].y, a1);
    a0 = fmaf(w1, f[1].x, a0); a1 = fmaf(w1, f[1].y, a1);
    a0 = fmaf(w2, f[2].x, a0); a1 = fmaf(w2, f[2].y, a1);
    a0 = fmaf(w3, f[3].x, a0); a1 = fmaf(w3, f[3].y, a1);
    a0 = fmaf(w4, f[4].x, a0); a1 = fmaf(w4, f[4].y, a1);
    a0 = fmaf(w5, f[5].x, a0); a1 = fmaf(w5, f[5].y, a1);
    a0 = fmaf(w6, f[6].x, a0); a1 = fmaf(w6, f[6].y, a1);
    a0 = fmaf(w7, f[7].x, a0); a1 = fmaf(w7, f[7].y, a1);
    return make_float2(a0, a1);
}

// ---------------- unified gather kernel ----------------
// One thread = one point = ALL 16 levels. Perfectly uniform work (no level
// imbalance). XCD-contiguous bijective chunk mapping: XCD j (= b&7 via
// round-robin dispatch) gets a contiguous 1/8 of the morton/tree-sorted
// chunks (~1 tree). Thread owns the whole 128 B out row -> writes two FULL
// 64 B lines, 4 back-to-back float4 stores each (no partial-line RMW, no
// ws2 round-trip, no k_final). Levels computed in two halves of 8 to keep
// live row state at 16 VGPR (target <=64 VGPR, 8 waves/SIMD).

__global__ __launch_bounds__(256, 8) void k_all(const float4* __restrict__ sorted,
                                                const float* __restrict__ params,
                                                float4* __restrict__ out4,
                                                int N, int nc) {
    const int b = blockIdx.x;
    const int q = nc >> 3, r = nc & 7;
    const int j = b & 7;
    const int chunk = j * q + min(j, r) + (b >> 3);   // bijective [0,nc)
    const int i = chunk * 256 + (int)threadIdx.x;
    if (i >= N) return;

    const float4 p = sorted[i];
    const unsigned wbits = __float_as_uint(p.w);
    const int n = (int)(wbits & 0xFFFFFFu);
    const int tree = (int)(wbits >> 24);

    #pragma unroll
    for (int h = 0; h < 2; ++h) {              // two 64 B half-rows
        float2 row[8];
        #pragma unroll
        for (int l = 0; l < 8; ++l) {
            float2 f[8]; float wx, wy, wz;
            level_load(p, tree, 8 * h + l, params, f, wx, wy, wz);
            row[l] = level_fma(f, wx, wy, wz);
        }
        // one full 64 B line: float4 slots 4h .. 4h+3, back-to-back
        #pragma unroll
        for (int k = 0; k < 4; ++k) {
            out4[(size_t)n * 8 + 4 * h + k] =
                make_float4(row[2 * k].x, row[2 * k].y,
                            row[2 * k + 1].x, row[2 * k + 1].y);
        }
    }
}

// ---------------- fallback (fused one-pass) ----------------

__global__ __launch_bounds__(256) void lotd_fwd_fused(
    const float* __restrict__ xs, const float* __restrict__ params,
    const int* __restrict__ inds, float* __restrict__ out, int N)
{
    const int g = blockIdx.x * 256 + threadIdx.x;
    const int n = g >> 4;
    if (n >= N) return;
    const int l = g & 15;
    const float rm1 = RM1_TAB[l];
    const int rmax = (int)rm1;
    const float x = xs[3 * n], y = xs[3 * n + 1], z = xs[3 * n + 2];
    const int tree = inds[n];
    const float px = (x * 0.5f + 0.5f) * rm1;
    const float py = (y * 0.5f + 0.5f) * rm1;
    const float pz = (z * 0.5f + 0.5f) * rm1;
    const float fx = floorf(px), fy = floorf(py), fz = floorf(pz);
    const float wx = px - fx, wy = py - fy, wz = pz - fz;
    const int ix = (int)fx, iy = (int)fy, iz = (int)fz;
    const int x0 = min(max(ix, 0), rmax), x1 = min(max(ix + 1, 0), rmax);
    const int y0 = min(max(iy, 0), rmax), y1 = min(max(iy + 1, 0), rmax);
    const int z0 = min(max(iz, 0), rmax), z1 = min(max(iz + 1, 0), rmax);
    const unsigned hx0 = (unsigned)x0, hx1 = (unsigned)x1;
    const unsigned hy0 = (unsigned)y0 * 2654435761u, hy1 = (unsigned)y1 * 2654435761u;
    const unsigned hz0 = (unsigned)z0 * 805459861u,  hz1 = (unsigned)z1 * 805459861u;
    const float2* tbl = (const float2*)(params + (size_t)(tree * NLEVELS + l) * (TSIZE * 2));
    const float2 f000 = tbl[(hx0 ^ hy0 ^ hz0) & TMASK];
    const float2 f001 = tbl[(hx0 ^ hy0 ^ hz1) & TMASK];
    const float2 f010 = tbl[(hx0 ^ hy1 ^ hz0) & TMASK];
    const float2 f011 = tbl[(hx0 ^ hy1 ^ hz1) & TMASK];
    const float2 f100 = tbl[(hx1 ^ hy0 ^ hz0) & TMASK];
    const float2 f101 = tbl[(hx1 ^ hy0 ^ hz1) & TMASK];
    const float2 f110 = tbl[(hx1 ^ hy1 ^ hz0) & TMASK];
    const float2 f111 = tbl[(hx1 ^ hy1 ^ hz1) & TMASK];
    const float wx0 = 1.f - wx, wy0 = 1.f - wy, wz0 = 1.f - wz;
    float a0 = 0.f, a1 = 0.f;
    a0 = fmaf(wx0*wy0*wz0, f000.x, a0); a1 = fmaf(wx0*wy0*wz0, f000.y, a1);
    a0 = fmaf(wx0*wy0*wz , f001.x, a0); a1 = fmaf(wx0*wy0*wz , f001.y, a1);
    a0 = fmaf(wx0*wy *wz0, f010.x, a0); a1 = fmaf(wx0*wy *wz0, f010.y, a1);
    a0 = fmaf(wx0*wy *wz , f011.x, a0); a1 = fmaf(wx0*wy *wz , f011.y, a1);
    a0 = fmaf(wx *wy0*wz0, f100.x, a0); a1 = fmaf(wx *wy0*wz0, f100.y, a1);
    a0 = fmaf(wx *wy0*wz , f101.x, a0); a1 = fmaf(wx *wy0*wz , f101.y, a1);
    a0 = fmaf(wx *wy *wz0, f110.x, a0); a1 = fmaf(wx *wy *wz0, f110.y, a1);
    a0 = fmaf(wx *wy *wz , f111.x, a0); a1 = fmaf(wx *wy *wz , f111.y, a1);
    ((float2*)out)[(size_t)n * 16 + l] = make_float2(a0, a1);
}

extern "C" void kernel_launch(void* const* d_in, const int* in_sizes, int n_in,
                              void* d_out, int out_size, void* d_ws, size_t ws_size,
                              hipStream_t stream) {
    const float* xs     = (const float*)d_in[0];
    const float* params = (const float*)d_in[1];
    const int*   inds   = (const int*)d_in[2];
    float*       out    = (float*)d_out;

    const int N = in_sizes[0] / 3;
    const int nc = (N + 255) / 256;

    const size_t hist_bytes   = (size_t)NBUCK * 4;               // 128 KB
    const size_t head_bytes   = 2 * hist_bytes;                  // hist + cursor
    const size_t sorted_bytes = ((size_t)N * 16 + 255) & ~(size_t)255;
    const size_t need = head_bytes + sorted_bytes;

    if (ws_size < need) {
        const int total = N * NLEVELS;
        lotd_fwd_fused<<<(total + 255) / 256, 256, 0, stream>>>(xs, params, inds, out, N);
        return;
    }

    unsigned* hist   = (unsigned*)d_ws;
    unsigned* cursor = (unsigned*)((char*)d_ws + hist_bytes);
    float4*   sorted = (float4*)((char*)d_ws + head_bytes);

    hipMemsetAsync(hist, 0, hist_bytes, stream);
    k_hist<<<nc, 256, 0, stream>>>(xs, inds, N, hist);
    k_scan<<<1, 1024, 0, stream>>>(hist, cursor);
    k_scatter<<<nc, 256, 0, stream>>>(xs, inds, N, cursor, sorted);

    k_all<<<nc, 256, 0, stream>>>(sorted, params, (float4*)out, N, nc);
}

// Round 10
// 815.193 us; speedup vs baseline: 2.8230x; 2.8230x over previous
//
#include <hip/hip_runtime.h>

#define NLEVELS 16
#define TSIZE 131072
#define TMASK (TSIZE - 1)
#define NBUCK 32768           // 8 trees x 4096 morton cells (4 bits/dim)

typedef float f32x4 __attribute__((ext_vector_type(4)));

__device__ __constant__ float RM1_TAB[16] = {
    15.f, 21.f, 29.f, 40.f, 54.f, 74.f, 101.f, 138.f,
    187.f, 255.f, 347.f, 471.f, 641.f, 871.f, 1183.f, 1607.f
};

// compile-time copy for template levels
constexpr float RM1_C[16] = {
    15.f, 21.f, 29.f, 40.f, 54.f, 74.f, 101.f, 138.f,
    187.f, 255.f, 347.f, 471.f, 641.f, 871.f, 1183.f, 1607.f
};

// spread 4 bits to stride-3 positions 0,3,6,9
__device__ __forceinline__ unsigned spread4(unsigned v) {
    v = (v | (v << 4)) & 0x0C3u;
    v = (v | (v << 2)) & 0x249u;
    return v;
}

__device__ __forceinline__ unsigned bucket_key(float x, float y, float z, unsigned tree) {
    const int cx = min(max((int)((x * 0.5f + 0.5f) * 16.f), 0), 15);
    const int cy = min(max((int)((y * 0.5f + 0.5f) * 16.f), 0), 15);
    const int cz = min(max((int)((z * 0.5f + 0.5f) * 16.f), 0), 15);
    const unsigned m = spread4((unsigned)cx) | (spread4((unsigned)cy) << 1)
                     | (spread4((unsigned)cz) << 2);
    return (tree << 12) | m;
}

// ---------------- counting sort by (tree, morton12) ----------------

__global__ __launch_bounds__(256) void k_hist(const float* __restrict__ xs,
                                              const int* __restrict__ inds, int N,
                                              unsigned* __restrict__ hist) {
    const int i = blockIdx.x * 256 + threadIdx.x;
    if (i >= N) return;
    const unsigned key = bucket_key(xs[3 * i], xs[3 * i + 1], xs[3 * i + 2],
                                    (unsigned)(inds[i] & 7));
    atomicAdd(&hist[key], 1u);
}

__global__ __launch_bounds__(1024) void k_scan(const unsigned* __restrict__ hist,
                                               unsigned* __restrict__ cursor) {
    __shared__ unsigned sums[1024];
    const int t = threadIdx.x;
    const int per = NBUCK / 1024;          // 32
    unsigned s = 0;
    #pragma unroll
    for (int j = 0; j < per; ++j) s += hist[t * per + j];
    sums[t] = s;
    __syncthreads();
    for (int off = 1; off < 1024; off <<= 1) {
        const unsigned add = (t >= off) ? sums[t - off] : 0u;
        __syncthreads();
        sums[t] += add;
        __syncthreads();
    }
    unsigned run = (t == 0) ? 0u : sums[t - 1];
    #pragma unroll
    for (int j = 0; j < per; ++j) {
        cursor[t * per + j] = run;
        run += hist[t * per + j];
    }
}

__global__ __launch_bounds__(256) void k_scatter(const float* __restrict__ xs,
                                                 const int* __restrict__ inds, int N,
                                                 unsigned* __restrict__ cursor,
                                                 float4* __restrict__ sorted) {
    const int i = blockIdx.x * 256 + threadIdx.x;
    if (i >= N) return;
    const float x = xs[3 * i], y = xs[3 * i + 1], z = xs[3 * i + 2];
    const unsigned tree = (unsigned)(inds[i] & 7);
    const unsigned key = bucket_key(x, y, z, tree);
    const unsigned pos = atomicAdd(&cursor[key], 1u);
    sorted[pos] = make_float4(x, y, z, __uint_as_float(((unsigned)i) | (tree << 24)));
}

// ---------------- one level, compile-time L, NO arrays anywhere ------------

template<int L>
__device__ __forceinline__ float2 level_one(const float4 p, int tree,
                                            const float* __restrict__ params) {
    constexpr float rm1 = RM1_C[L];
    constexpr int rmax = (int)rm1;

    const float px = (p.x * 0.5f + 0.5f) * rm1;
    const float py = (p.y * 0.5f + 0.5f) * rm1;
    const float pz = (p.z * 0.5f + 0.5f) * rm1;
    const float fx = floorf(px), fy = floorf(py), fz = floorf(pz);
    const float wx = px - fx, wy = py - fy, wz = pz - fz;
    const int ix = (int)fx, iy = (int)fy, iz = (int)fz;

    const int x0 = min(max(ix, 0), rmax), x1 = min(max(ix + 1, 0), rmax);
    const int y0 = min(max(iy, 0), rmax), y1 = min(max(iy + 1, 0), rmax);
    const int z0 = min(max(iz, 0), rmax), z1 = min(max(iz + 1, 0), rmax);

    const unsigned hx0 = (unsigned)x0;
    const unsigned hx1 = (unsigned)x1;
    const unsigned hy0 = (unsigned)y0 * 2654435761u;
    const unsigned hy1 = (unsigned)y1 * 2654435761u;
    const unsigned hz0 = (unsigned)z0 * 805459861u;
    const unsigned hz1 = (unsigned)z1 * 805459861u;

    const float2* __restrict__ tbl =
        (const float2*)(params + (size_t)(tree * NLEVELS + L) * (TSIZE * 2));

    const unsigned m00 = hy0 ^ hz0;
    const unsigned m01 = hy0 ^ hz1;
    const unsigned m10 = hy1 ^ hz0;
    const unsigned m11 = hy1 ^ hz1;
    const unsigned i000 = (hx0 ^ m00) & TMASK;
    const unsigned i001 = (hx0 ^ m01) & TMASK;
    const unsigned i010 = (hx0 ^ m10) & TMASK;
    const unsigned i011 = (hx0 ^ m11) & TMASK;

    float2 f0, f1, f2, f3, f4, f5, f6, f7;   // named registers only

    // x-prime is 1: if x0 even and x1==x0+1, the two x-corners are ADJACENT
    // table entries {2j,2j+1} -> one aligned float4 covers both.
    const bool pairOK = ((x0 & 1) == 0) && (x1 == x0 + 1);
    if (pairOK) {
        const float4* __restrict__ tbl4 = (const float4*)tbl;
        const float4 q00 = tbl4[i000 >> 1];
        const float4 q01 = tbl4[i001 >> 1];
        const float4 q10 = tbl4[i010 >> 1];
        const float4 q11 = tbl4[i011 >> 1];
        f0 = (i000 & 1) ? make_float2(q00.z, q00.w) : make_float2(q00.x, q00.y);
        f4 = (i000 & 1) ? make_float2(q00.x, q00.y) : make_float2(q00.z, q00.w);
        f1 = (i001 & 1) ? make_float2(q01.z, q01.w) : make_float2(q01.x, q01.y);
        f5 = (i001 & 1) ? make_float2(q01.x, q01.y) : make_float2(q01.z, q01.w);
        f2 = (i010 & 1) ? make_float2(q10.z, q10.w) : make_float2(q10.x, q10.y);
        f6 = (i010 & 1) ? make_float2(q10.x, q10.y) : make_float2(q10.z, q10.w);
        f3 = (i011 & 1) ? make_float2(q11.z, q11.w) : make_float2(q11.x, q11.y);
        f7 = (i011 & 1) ? make_float2(q11.x, q11.y) : make_float2(q11.z, q11.w);
    } else {
        const unsigned i100 = (hx1 ^ m00) & TMASK;
        const unsigned i101 = (hx1 ^ m01) & TMASK;
        const unsigned i110 = (hx1 ^ m10) & TMASK;
        const unsigned i111 = (hx1 ^ m11) & TMASK;
        f0 = tbl[i000]; f1 = tbl[i001];
        f2 = tbl[i010]; f3 = tbl[i011];
        f4 = tbl[i100]; f5 = tbl[i101];
        f6 = tbl[i110]; f7 = tbl[i111];
    }

    const float wx0 = 1.f - wx, wy0 = 1.f - wy, wz0 = 1.f - wz;
    const float w0 = wx0 * wy0 * wz0;
    const float w1 = wx0 * wy0 * wz;
    const float w2 = wx0 * wy  * wz0;
    const float w3 = wx0 * wy  * wz;
    const float w4 = wx  * wy0 * wz0;
    const float w5 = wx  * wy0 * wz;
    const float w6 = wx  * wy  * wz0;
    const float w7 = wx  * wy  * wz;

    float a0 = 0.f, a1 = 0.f;
    a0 = fmaf(w0, f0.x, a0); a1 = fmaf(w0, f0.y, a1);
    a0 = fmaf(w1, f1.x, a0); a1 = fmaf(w1, f1.y, a1);
    a0 = fmaf(w2, f2.x, a0); a1 = fmaf(w2, f2.y, a1);
    a0 = fmaf(w3, f3.x, a0); a1 = fmaf(w3, f3.y, a1);
    a0 = fmaf(w4, f4.x, a0); a1 = fmaf(w4, f4.y, a1);
    a0 = fmaf(w5, f5.x, a0); a1 = fmaf(w5, f5.y, a1);
    a0 = fmaf(w6, f6.x, a0); a1 = fmaf(w6, f6.y, a1);
    a0 = fmaf(w7, f7.x, a0); a1 = fmaf(w7, f7.y, a1);
    return make_float2(a0, a1);
}

// ---------------- unified gather kernel ----------------
// One thread = one point = ALL 16 levels (uniform work, no imbalance).
// XCD-contiguous bijective chunk map: XCD j (= b&7 round-robin) gets a
// contiguous 1/8 of the tree/morton-sorted chunks (~1 tree). Thread owns the
// whole 128 B out row -> two FULL 64 B lines, 4 back-to-back float4 stores
// each. NO arrays, NO forced occupancy bound -> nothing can spill to scratch.

__global__ __launch_bounds__(256) void k_all(const float4* __restrict__ sorted,
                                             const float* __restrict__ params,
                                             float4* __restrict__ out4,
                                             int N, int nc) {
    const int b = blockIdx.x;
    const int q = nc >> 3, r = nc & 7;
    const int j = b & 7;
    const int chunk = j * q + min(j, r) + (b >> 3);   // bijective [0,nc)
    const int i = chunk * 256 + (int)threadIdx.x;
    if (i >= N) return;

    const float4 p = sorted[i];
    const unsigned wbits = __float_as_uint(p.w);
    const int n = (int)(wbits & 0xFFFFFFu);
    const int tree = (int)(wbits >> 24);

    {   // levels 0..7 -> out float4 slots 0..3 (one full 64 B line)
        const float2 r0 = level_one<0>(p, tree, params);
        const float2 r1 = level_one<1>(p, tree, params);
        const float2 r2 = level_one<2>(p, tree, params);
        const float2 r3 = level_one<3>(p, tree, params);
        const float2 r4 = level_one<4>(p, tree, params);
        const float2 r5 = level_one<5>(p, tree, params);
        const float2 r6 = level_one<6>(p, tree, params);
        const float2 r7 = level_one<7>(p, tree, params);
        out4[(size_t)n * 8 + 0] = make_float4(r0.x, r0.y, r1.x, r1.y);
        out4[(size_t)n * 8 + 1] = make_float4(r2.x, r2.y, r3.x, r3.y);
        out4[(size_t)n * 8 + 2] = make_float4(r4.x, r4.y, r5.x, r5.y);
        out4[(size_t)n * 8 + 3] = make_float4(r6.x, r6.y, r7.x, r7.y);
    }
    {   // levels 8..15 -> out float4 slots 4..7
        const float2 r0 = level_one<8>(p, tree, params);
        const float2 r1 = level_one<9>(p, tree, params);
        const float2 r2 = level_one<10>(p, tree, params);
        const float2 r3 = level_one<11>(p, tree, params);
        const float2 r4 = level_one<12>(p, tree, params);
        const float2 r5 = level_one<13>(p, tree, params);
        const float2 r6 = level_one<14>(p, tree, params);
        const float2 r7 = level_one<15>(p, tree, params);
        out4[(size_t)n * 8 + 4] = make_float4(r0.x, r0.y, r1.x, r1.y);
        out4[(size_t)n * 8 + 5] = make_float4(r2.x, r2.y, r3.x, r3.y);
        out4[(size_t)n * 8 + 6] = make_float4(r4.x, r4.y, r5.x, r5.y);
        out4[(size_t)n * 8 + 7] = make_float4(r6.x, r6.y, r7.x, r7.y);
    }
}

// ---------------- fallback (fused one-pass) ----------------

__global__ __launch_bounds__(256) void lotd_fwd_fused(
    const float* __restrict__ xs, const float* __restrict__ params,
    const int* __restrict__ inds, float* __restrict__ out, int N)
{
    const int g = blockIdx.x * 256 + threadIdx.x;
    const int n = g >> 4;
    if (n >= N) return;
    const int l = g & 15;
    const float rm1 = RM1_TAB[l];
    const int rmax = (int)rm1;
    const float x = xs[3 * n], y = xs[3 * n + 1], z = xs[3 * n + 2];
    const int tree = inds[n];
    const float px = (x * 0.5f + 0.5f) * rm1;
    const float py = (y * 0.5f + 0.5f) * rm1;
    const float pz = (z * 0.5f + 0.5f) * rm1;
    const float fx = floorf(px), fy = floorf(py), fz = floorf(pz);
    const float wx = px - fx, wy = py - fy, wz = pz - fz;
    const int ix = (int)fx, iy = (int)fy, iz = (int)fz;
    const int x0 = min(max(ix, 0), rmax), x1 = min(max(ix + 1, 0), rmax);
    const int y0 = min(max(iy, 0), rmax), y1 = min(max(iy + 1, 0), rmax);
    const int z0 = min(max(iz, 0), rmax), z1 = min(max(iz + 1, 0), rmax);
    const unsigned hx0 = (unsigned)x0, hx1 = (unsigned)x1;
    const unsigned hy0 = (unsigned)y0 * 2654435761u, hy1 = (unsigned)y1 * 2654435761u;
    const unsigned hz0 = (unsigned)z0 * 805459861u,  hz1 = (unsigned)z1 * 805459861u;
    const float2* tbl = (const float2*)(params + (size_t)(tree * NLEVELS + l) * (TSIZE * 2));
    const float2 f000 = tbl[(hx0 ^ hy0 ^ hz0) & TMASK];
    const float2 f001 = tbl[(hx0 ^ hy0 ^ hz1) & TMASK];
    const float2 f010 = tbl[(hx0 ^ hy1 ^ hz0) & TMASK];
    const float2 f011 = tbl[(hx0 ^ hy1 ^ hz1) & TMASK];
    const float2 f100 = tbl[(hx1 ^ hy0 ^ hz0) & TMASK];
    const float2 f101 = tbl[(hx1 ^ hy0 ^ hz1) & TMASK];
    const float2 f110 = tbl[(hx1 ^ hy1 ^ hz0) & TMASK];
    const float2 f111 = tbl[(hx1 ^ hy1 ^ hz1) & TMASK];
    const float wx0 = 1.f - wx, wy0 = 1.f - wy, wz0 = 1.f - wz;
    float a0 = 0.f, a1 = 0.f;
    a0 = fmaf(wx0*wy0*wz0, f000.x, a0); a1 = fmaf(wx0*wy0*wz0, f000.y, a1);
    a0 = fmaf(wx0*wy0*wz , f001.x, a0); a1 = fmaf(wx0*wy0*wz , f001.y, a1);
    a0 = fmaf(wx0*wy *wz0, f010.x, a0); a1 = fmaf(wx0*wy *wz0, f010.y, a1);
    a0 = fmaf(wx0*wy *wz , f011.x, a0); a1 = fmaf(wx0*wy *wz , f011.y, a1);
    a0 = fmaf(wx *wy0*wz0, f100.x, a0); a1 = fmaf(wx *wy0*wz0, f100.y, a1);
    a0 = fmaf(wx *wy0*wz , f101.x, a0); a1 = fmaf(wx *wy0*wz , f101.y, a1);
    a0 = fmaf(wx *wy *wz0, f110.x, a0); a1 = fmaf(wx *wy *wz0, f110.y, a1);
    a0 = fmaf(wx *wy *wz , f111.x, a0); a1 = fmaf(wx *wy *wz , f111.y, a1);
    ((float2*)out)[(size_t)n * 16 + l] = make_float2(a0, a1);
}

extern "C" void kernel_launch(void* const* d_in, const int* in_sizes, int n_in,
                              void* d_out, int out_size, void* d_ws, size_t ws_size,
                              hipStream_t stream) {
    const float* xs     = (const float*)d_in[0];
    const float* params = (const float*)d_in[1];
    const int*   inds   = (const int*)d_in[2];
    float*       out    = (float*)d_out;

    const int N = in_sizes[0] / 3;
    const int nc = (N + 255) / 256;

    const size_t hist_bytes   = (size_t)NBUCK * 4;               // 128 KB
    const size_t head_bytes   = 2 * hist_bytes;                  // hist + cursor
    const size_t sorted_bytes = ((size_t)N * 16 + 255) & ~(size_t)255;
    const size_t need = head_bytes + sorted_bytes;

    if (ws_size < need) {
        const int total = N * NLEVELS;
        lotd_fwd_fused<<<(total + 255) / 256, 256, 0, stream>>>(xs, params, inds, out, N);
        return;
    }

    unsigned* hist   = (unsigned*)d_ws;
    unsigned* cursor = (unsigned*)((char*)d_ws + hist_bytes);
    float4*   sorted = (float4*)((char*)d_ws + head_bytes);

    hipMemsetAsync(hist, 0, hist_bytes, stream);
    k_hist<<<nc, 256, 0, stream>>>(xs, inds, N, hist);
    k_scan<<<1, 1024, 0, stream>>>(hist, cursor);
    k_scatter<<<nc, 256, 0, stream>>>(xs, inds, N, cursor, sorted);

    k_all<<<nc, 256, 0, stream>>>(sorted, params, (float4*)out, N, nc);
}